// Round 8
// baseline (652.510 us; speedup 1.0000x reference)
//
#include <hip/hip_runtime.h>

#define AS1 __attribute__((address_space(1)))
#define AS3 __attribute__((address_space(3)))

typedef __bf16 bf16x8 __attribute__((ext_vector_type(8)));
typedef float f32x4 __attribute__((ext_vector_type(4)));

// round-to-nearest-even f32 -> bf16
__device__ __forceinline__ unsigned short f2bf(float f) {
  union { float f; unsigned u; } v; v.f = f;
  unsigned u = v.u;
  unsigned r = (u + 0x7fffu + ((u >> 16) & 1u)) >> 16;
  return (unsigned short)r;
}

// ---------------------------------------------------------------------------
// dcalc stage A: partial[is][b][o] = sum_{i in chunk is} ysq[b,i] * W[i,o]^2
// ---------------------------------------------------------------------------
__global__ __launch_bounds__(256) void dcalc_a_kernel(const float* __restrict__ y,
                                                      const float* __restrict__ W,
                                                      float* __restrict__ partial) {
  __shared__ float ysq[32][32];  // [i_local][b]
  const int o = blockIdx.x * 256 + threadIdx.x;
  const int i0 = blockIdx.y * 32;
  for (int e = threadIdx.x; e < 1024; e += 256) {
    int il = e >> 5, b = e & 31;
    float t = y[b * 1024 + i0 + il] * 0.03125f;
    ysq[il][b] = t * t;
  }
  __syncthreads();

  f32x4 acc[8] = {};
#pragma unroll
  for (int il = 0; il < 32; ++il) {
    float w = W[(size_t)(i0 + il) * 1024 + o];
    float w2 = w * w;
#pragma unroll
    for (int b4 = 0; b4 < 8; ++b4) {
      f32x4 q = *(const f32x4*)&ysq[il][b4 * 4];
#pragma unroll
      for (int k = 0; k < 4; ++k) acc[b4][k] = fmaf(q[k], w2, acc[b4][k]);
    }
  }
  float* p = partial + (size_t)blockIdx.y * 32768 + o;
#pragma unroll
  for (int b4 = 0; b4 < 8; ++b4)
#pragma unroll
    for (int k = 0; k < 4; ++k) p[(b4 * 4 + k) * 1024] = acc[b4][k];
}

// ---------------------------------------------------------------------------
// dcalc stage B: dmod[b,o] = rsqrt( sum_is partial[is][b][o] + 1e-8 )
// ---------------------------------------------------------------------------
__global__ __launch_bounds__(256) void dcalc_b_kernel(const float* __restrict__ partial,
                                                      float* __restrict__ dmod) {
  const int bo = blockIdx.x * 256 + threadIdx.x;
  float acc = 0.f;
#pragma unroll 8
  for (int is = 0; is < 32; ++is) acc += partial[(size_t)is * 32768 + bo];
  dmod[bo] = rsqrtf(acc + 1e-8f);
}

// ---------------------------------------------------------------------------
// WT[o,i] = bf16(W[i,o])
// ---------------------------------------------------------------------------
__global__ void wconv_kernel(const float* __restrict__ W,
                             unsigned short* __restrict__ WT) {
  __shared__ float t[32][33];
  const int tx = threadIdx.x;
  const int ty = threadIdx.y;
  const int i0 = blockIdx.y * 32;
  const int o0 = blockIdx.x * 32;
#pragma unroll
  for (int k = 0; k < 4; ++k)
    t[ty + k * 8][tx] = W[(size_t)(i0 + ty + k * 8) * 1024 + o0 + tx];
  __syncthreads();
#pragma unroll
  for (int k = 0; k < 4; ++k)
    WT[(size_t)(o0 + ty + k * 8) * 1024 + i0 + tx] = f2bf(t[tx][ty + k * 8]);
}

// ---------------------------------------------------------------------------
// X[m,i] = bf16(Efou[m,i] * y[b,i]/32)
// ---------------------------------------------------------------------------
__global__ __launch_bounds__(256) void xconv_kernel(const float4* __restrict__ E4,
                                                    const float* __restrict__ y,
                                                    unsigned short* __restrict__ X) {
  const size_t total = (size_t)8388608;  // 32*1024*1024/4
  for (size_t g = (size_t)blockIdx.x * blockDim.x + threadIdx.x; g < total;
       g += (size_t)gridDim.x * blockDim.x) {
    float4 v = E4[g];
    size_t e = g * 4;
    int i = (int)(e & 1023);
    int b = (int)(e >> 20);
    float4 yv = *(const float4*)(y + b * 1024 + i);
    ushort4 o;
    o.x = f2bf(v.x * yv.x * 0.03125f);
    o.y = f2bf(v.y * yv.y * 0.03125f);
    o.z = f2bf(v.z * yv.z * 0.03125f);
    o.w = f2bf(v.w * yv.w * 0.03125f);
    *(ushort4*)(X + e) = o;
  }
}

// ---------------------------------------------------------------------------
// GEMM: out[m,o] = (X @ W)[m,o] * d[m>>10, o]
// 256x256 tile, BK=32, 512 thr (8 waves 2Mx4N), 64KB LDS double-buffer ->
// 2 blocks/CU, ALL 512 blocks resident: barrier/vmcnt drains of one block
// overlap with the co-resident block's MFMA (m114/m97 mechanism).
// One barrier per K-tile. Swizzle: 64B rows, slot ^= (row&3); read-side XOR
// matched by pre-swizzled global source (rule #21). XCD grouping: each XCD
// owns 16 consecutive bm panels (all 4 bn) -> X panel fetched once per XCD.
// ---------------------------------------------------------------------------
#define BAR __builtin_amdgcn_s_barrier()
#define LGKM0 asm volatile("s_waitcnt lgkmcnt(0)" ::: "memory")
#define VM(n) asm volatile("s_waitcnt vmcnt(" #n ")" ::: "memory")
#define SCHB __builtin_amdgcn_sched_barrier(0)
#define PRIO(x) __builtin_amdgcn_s_setprio(x)

// stage K-tile kt (A 16KB + B 16KB) into dst buffer: 4 gload_lds per thread
#define STG(kt, dst)                                                          \
  do {                                                                        \
    __builtin_amdgcn_global_load_lds((const AS1 void*)(Xs + (kt) * 64),       \
                                     (AS3 void*)((dst) + u16), 16, 0, 0);     \
    __builtin_amdgcn_global_load_lds(                                         \
        (const AS1 void*)(Xs + 262144 + (kt) * 64),                           \
        (AS3 void*)((dst) + 8192 + u16), 16, 0, 0);                           \
    __builtin_amdgcn_global_load_lds((const AS1 void*)(Ws + (kt) * 64),       \
                                     (AS3 void*)((dst) + 16384 + u16), 16, 0, \
                                     0);                                      \
    __builtin_amdgcn_global_load_lds(                                         \
        (const AS1 void*)(Ws + 262144 + (kt) * 64),                           \
        (AS3 void*)((dst) + 24576 + u16), 16, 0, 0);                          \
  } while (0)

// swizzled fragment reads: row&3 == l15&3 for all frags
#define RD_A(mi)                                                             \
  (*(const bf16x8*)(Ab + (wr * 128 + (mi) * 16 + l15) * 64 +                 \
                    ((lhi * 16) ^ swz)))
#define RD_B(nf)                                                             \
  (*(const bf16x8*)(Ab + 16384 + (wc * 64 + (nf) * 16 + l15) * 64 +          \
                    ((lhi * 16) ^ swz)))

__global__ __launch_bounds__(512, 4) void gemm2b_kernel(
    const unsigned short* __restrict__ X, const unsigned short* __restrict__ WT,
    const float* __restrict__ dmod, float* __restrict__ out) {
  extern __shared__ char lds[];
  const int tid = threadIdx.x;
  const int bid = blockIdx.x;                  // 0..511
  const int wg = (bid & 7) * 64 + (bid >> 3);  // XCD x -> bm in [16x,16x+16)
  const int bm = wg >> 2, bn = wg & 3;
  const int m0 = bm * 256, n0 = bn * 256;

  const int w = tid >> 6, l = tid & 63;
  const int wr = w >> 2, wc = w & 3;  // 2M x 4N waves, per-wave 128x64
  const int l15 = l & 15, lhi = l >> 4;
  const int swz = (l15 & 3) << 4;

  // staging source: row = srow (+128 for 2nd gload), pre-swizzled k-slot
  const int srow = tid >> 2;                 // 0..127
  const int xs = (tid & 3) ^ (srow & 3);     // inverse of read-side XOR
  const char* Xs = (const char*)X + (size_t)(m0 + srow) * 2048 + xs * 16;
  const char* Ws = (const char*)WT + (size_t)(n0 + srow) * 2048 + xs * 16;
  const int u16 = tid * 16;

  f32x4 acc[8][4] = {};
  bf16x8 a[8], bfr[4];

  // prologue: stage tile 0, drain, go
  STG(0, lds);
  VM(0);
  BAR;

  for (int t = 0; t < 32; ++t) {
    const char* Ab = lds + (t & 1) * 32768;
    char* dN = lds + ((t + 1) & 1) * 32768;
    if (t < 31) STG(t + 1, dN);  // buf written was last read at tile t-1
#pragma unroll
    for (int mi = 0; mi < 8; ++mi) a[mi] = RD_A(mi);
#pragma unroll
    for (int nf = 0; nf < 4; ++nf) bfr[nf] = RD_B(nf);
    LGKM0; SCHB;
    PRIO(1);
#pragma unroll
    for (int mi = 0; mi < 8; ++mi)
#pragma unroll
      for (int nf = 0; nf < 4; ++nf)
        acc[mi][nf] = __builtin_amdgcn_mfma_f32_16x16x32_bf16(
            a[mi], bfr[nf], acc[mi][nf], 0, 0, 0);
    PRIO(0); SCHB;
    if (t < 31) { VM(0); }  // tile t+1 staged; drain overlaps co-resident blk
    BAR;
  }

  // epilogue: C/D layout col=l&15, row=(l>>4)*4+j; scale by d[b,o]
  const int b = m0 >> 10;  // 256 | 1024 -> uniform per block
  const int col0 = n0 + wc * 64 + l15;
  float dv[4];
#pragma unroll
  for (int nf = 0; nf < 4; ++nf) dv[nf] = dmod[b * 1024 + col0 + nf * 16];
#pragma unroll
  for (int mf = 0; mf < 8; ++mf) {
#pragma unroll
    for (int j = 0; j < 4; ++j) {
      const int row = m0 + wr * 128 + mf * 16 + lhi * 4 + j;
      float* orow = out + (size_t)row * 1024 + col0;
#pragma unroll
      for (int nf = 0; nf < 4; ++nf) orow[nf * 16] = acc[mf][nf][j] * dv[nf];
    }
  }
}

// ---------------------------------------------------------------------------
extern "C" void kernel_launch(void* const* d_in, const int* in_sizes, int n_in,
                              void* d_out, int out_size, void* d_ws, size_t ws_size,
                              hipStream_t stream) {
  const float* Efou = (const float*)d_in[0];  // 32*1024*1024 fp32
  const float* y    = (const float*)d_in[1];  // 32*1024 fp32
  const float* W    = (const float*)d_in[2];  // 1024*1024 fp32
  float* out = (float*)d_out;

  unsigned short* X  = (unsigned short*)d_ws;               // 64 MB bf16
  unsigned short* WT = X + (size_t)32768 * 1024;            // 2 MB bf16
  float* dmod        = (float*)(WT + (size_t)1024 * 1024);  // 128 KB fp32
  float* dpart       = dmod + 32768;                        // 4 MB fp32

  hipFuncSetAttribute((const void*)gemm2b_kernel,
                      hipFuncAttributeMaxDynamicSharedMemorySize, 65536);

  dcalc_a_kernel<<<dim3(4, 32), 256, 0, stream>>>(y, W, dpart);
  dcalc_b_kernel<<<128, 256, 0, stream>>>(dpart, dmod);
  wconv_kernel<<<dim3(32, 32), dim3(32, 8), 0, stream>>>(W, WT);
  xconv_kernel<<<2048, 256, 0, stream>>>((const float4*)Efou, y, X);
  gemm2b_kernel<<<512, 512, 65536, stream>>>(X, WT, dmod, out);
}

// Round 9
// 135.053 us; speedup vs baseline: 4.8315x; 4.8315x over previous
//
#include <hip/hip_runtime.h>

#define AS1 __attribute__((address_space(1)))
#define AS3 __attribute__((address_space(3)))

typedef __bf16 bf16x8 __attribute__((ext_vector_type(8)));
typedef float f32x4 __attribute__((ext_vector_type(4)));
typedef unsigned short ushort8 __attribute__((ext_vector_type(8)));

// round-to-nearest-even f32 -> bf16
__device__ __forceinline__ unsigned short f2bf(float f) {
  union { float f; unsigned u; } v; v.f = f;
  unsigned u = v.u;
  unsigned r = (u + 0x7fffu + ((u >> 16) & 1u)) >> 16;
  return (unsigned short)r;
}

// ---------------------------------------------------------------------------
// prep: fused dcalc_a + wconv. Grid (4 o-chunks, 32 i-chunks), block 256.
// Reads each W element ONCE: accumulates partial[is][b][o] (32 batches per
// element, latency hidden by 32 indep FMA chains) AND writes WT[o][i] bf16.
// ---------------------------------------------------------------------------
__global__ __launch_bounds__(256) void prep_kernel(const float* __restrict__ y,
                                                   const float* __restrict__ W,
                                                   float* __restrict__ partial,
                                                   unsigned short* __restrict__ WT) {
  __shared__ float ysq[32][32];  // [i_local][b]
  const int o = blockIdx.x * 256 + threadIdx.x;
  const int i0 = blockIdx.y * 32;
  for (int e = threadIdx.x; e < 1024; e += 256) {
    int il = e >> 5, b = e & 31;
    float t = y[b * 1024 + i0 + il] * 0.03125f;
    ysq[il][b] = t * t;
  }
  __syncthreads();

  f32x4 acc[8] = {};
  ushort8 wb[4];
#pragma unroll
  for (int il = 0; il < 32; ++il) {
    float w = W[(size_t)(i0 + il) * 1024 + o];
    wb[il >> 3][il & 7] = f2bf(w);
    float w2 = w * w;
#pragma unroll
    for (int b4 = 0; b4 < 8; ++b4) {
      f32x4 q = *(const f32x4*)&ysq[il][b4 * 4];
#pragma unroll
      for (int k = 0; k < 4; ++k) acc[b4][k] = fmaf(q[k], w2, acc[b4][k]);
    }
  }
  // WT row chunk: [o][i0..i0+32) = 64 contiguous bytes
  unsigned short* wt = WT + (size_t)o * 1024 + i0;
#pragma unroll
  for (int q = 0; q < 4; ++q) *(ushort8*)(wt + q * 8) = wb[q];
  // partial[is][b][o]
  float* p = partial + (size_t)blockIdx.y * 32768 + o;
#pragma unroll
  for (int b4 = 0; b4 < 8; ++b4)
#pragma unroll
    for (int k = 0; k < 4; ++k) p[(b4 * 4 + k) * 1024] = acc[b4][k];
}

// ---------------------------------------------------------------------------
// X[m,i] = bf16(Efou[m,i] * y[b,i]/32)
// ---------------------------------------------------------------------------
__global__ __launch_bounds__(256) void xconv_kernel(const float4* __restrict__ E4,
                                                    const float* __restrict__ y,
                                                    unsigned short* __restrict__ X) {
  const size_t total = (size_t)8388608;  // 32*1024*1024/4
  for (size_t g = (size_t)blockIdx.x * blockDim.x + threadIdx.x; g < total;
       g += (size_t)gridDim.x * blockDim.x) {
    float4 v = E4[g];
    size_t e = g * 4;
    int i = (int)(e & 1023);
    int b = (int)(e >> 20);
    float4 yv = *(const float4*)(y + b * 1024 + i);
    ushort4 o;
    o.x = f2bf(v.x * yv.x * 0.03125f);
    o.y = f2bf(v.y * yv.y * 0.03125f);
    o.z = f2bf(v.z * yv.z * 0.03125f);
    o.w = f2bf(v.w * yv.w * 0.03125f);
    *(ushort4*)(X + e) = o;
  }
}

// ---------------------------------------------------------------------------
// GEMM: out[m,o] = (X @ W)[m,o] * rsqrt(sum_is dpart[is][b][o] + eps)
// r6's verified gemm8d (82.5us) + dcalc_b folded into the prologue (dtab in
// LDS). 256x256 tile, BK=64, 8 waves 2Mx4N, deep-pipelined staging:
// B(t+1) at ph1/2, A(t+2) at ph3/4, ONE VM(4) per K-tile. XOR-swizzled LDS
// (pre-swizzled global source, rule #21), XCD swizzle, setprio.
// ---------------------------------------------------------------------------
#define NT 16           // K / BK
#define LDS_TILE 65536  // per-buffer: A 32KB + B 32KB

#define BAR __builtin_amdgcn_s_barrier()
#define LGKM0 asm volatile("s_waitcnt lgkmcnt(0)" ::: "memory")
#define VM(n) asm volatile("s_waitcnt vmcnt(" #n ")" ::: "memory")
#define SCHB __builtin_amdgcn_sched_barrier(0)
#define PRIO(x) __builtin_amdgcn_s_setprio(x)

#define STG_A(r, t, dst)                                                     \
  __builtin_amdgcn_global_load_lds(                                          \
      (const AS1 void*)(Xs + (size_t)(r) * 64 * 2048 + (t) * 128),           \
      (AS3 void*)((dst) + (r) * 8192 + sldso), 16, 0, 0)
#define STG_B(r, t, dst)                                                     \
  __builtin_amdgcn_global_load_lds(                                          \
      (const AS1 void*)(Ws + (size_t)(r) * 64 * 2048 + (t) * 128),           \
      (AS3 void*)((dst) + 32768 + (r) * 8192 + sldso), 16, 0, 0)

// swizzled fragment reads (row&7 == l15&7 for all frags)
#define RD_A(mh, mi, kk)                                                     \
  (*(const bf16x8*)(Ab + (wr * 128 + ((mh) * 4 + (mi)) * 16 + l15) * 128 +   \
                    ((((kk) * 64 + lhi * 16)) ^ swz_rd)))
#define RD_B(nh, ni, kk)                                                     \
  (*(const bf16x8*)(Bb + (wc * 64 + ((nh) * 2 + (ni)) * 16 + l15) * 128 +    \
                    ((((kk) * 64 + lhi * 16)) ^ swz_rd)))

#define LD_A(mh)                                                             \
  { _Pragma("unroll") for (int mi = 0; mi < 4; ++mi)                         \
      _Pragma("unroll") for (int kk = 0; kk < 2; ++kk)                       \
        a[mi][kk] = RD_A(mh, mi, kk); }
#define LD_B(nh)                                                             \
  { _Pragma("unroll") for (int ni = 0; ni < 2; ++ni)                         \
      _Pragma("unroll") for (int kk = 0; kk < 2; ++kk)                       \
        bfr[ni][kk] = RD_B(nh, ni, kk); }

#define MM(mh, nh)                                                           \
  do {                                                                       \
    _Pragma("unroll") for (int mi = 0; mi < 4; ++mi)                         \
      _Pragma("unroll") for (int ni = 0; ni < 2; ++ni)                       \
        _Pragma("unroll") for (int kk = 0; kk < 2; ++kk)                     \
          acc[(mh) * 4 + mi][(nh) * 2 + ni] =                                \
              __builtin_amdgcn_mfma_f32_16x16x32_bf16(                       \
                  a[mi][kk], bfr[ni][kk], acc[(mh) * 4 + mi][(nh) * 2 + ni], \
                  0, 0, 0);                                                  \
  } while (0)

__global__ __launch_bounds__(512, 2) void gemm8d_kernel(
    const unsigned short* __restrict__ X, const unsigned short* __restrict__ WT,
    const float* __restrict__ dpart, float* __restrict__ out) {
  extern __shared__ char lds[];
  float* dtab = (float*)(lds + 2 * LDS_TILE);  // 1KB: d for this block's cols

  const int tid = threadIdx.x;
  const int bid = blockIdx.x;                  // 0..511
  const int wg = (bid & 7) * 64 + (bid >> 3);  // bijective XCD swizzle
  const int bm = wg >> 2, bn = wg & 3;
  const int m0 = bm * 256, n0 = bn * 256;
  const int b = m0 >> 10;  // 256 | 1024 -> uniform per block

  const int w = tid >> 6, l = tid & 63;
  const int wr = w >> 2, wc = w & 3;  // 2M x 4N waves
  const int l15 = l & 15, lhi = l >> 4;
  const int swz_rd = (l15 & 7) << 4;

  // staging: LDS written linearly; SOURCE column pre-swizzled (rule #21)
  const int srow = tid >> 3;
  const int scb = ((tid & 7) << 4) ^ ((srow & 7) << 4);
  const char* Xs = (const char*)X + (size_t)(m0 + srow) * 2048 + scb;
  const char* Ws = (const char*)WT + (size_t)(n0 + srow) * 2048 + scb;
  const int sldso = tid * 16;

  f32x4 acc[8][4] = {};
  bf16x8 a[4][2], bfr[2][2];

  char* buf0 = lds;
  char* buf1 = lds + LDS_TILE;

  // ---- prologue A: fold dcalc_b -- dtab[c] = rsqrt(sum_is dpart + eps) ----
  if (tid < 256) {
    const float* dp = dpart + b * 1024 + n0 + tid;
    float s = 0.f;
#pragma unroll 8
    for (int is = 0; is < 32; ++is) s += dp[(size_t)is * 32768];
    dtab[tid] = rsqrtf(s + 1e-8f);
  }
  __syncthreads();  // dtab published; compiler has drained dpart loads

  // ---- prologue B: tile0 full (8) + A(1) (4) = 12 in flight ----
  STG_A(0, 0, buf0); STG_A(2, 0, buf0); STG_A(1, 0, buf0); STG_A(3, 0, buf0);
  STG_B(0, 0, buf0); STG_B(1, 0, buf0); STG_B(2, 0, buf0); STG_B(3, 0, buf0);
  STG_A(0, 1, buf1); STG_A(2, 1, buf1); STG_A(1, 1, buf1); STG_A(3, 1, buf1);
  VM(4);
  BAR;

  // steady tiles 0..13: B(t+1) at ph1/2, A(t+2) at ph3/4, VM(4) at ph4 end
  for (int t = 0; t < NT - 2; ++t) {
    const char* Ab = lds + (t & 1) * LDS_TILE;
    const char* Bb = Ab + 32768;
    char* dB = lds + ((t + 1) & 1) * LDS_TILE;  // B(t+1) dest
    char* dA = lds + (t & 1) * LDS_TILE;        // A(t+2) dest (current buf)
    const int t1 = t + 1, t2 = t + 2;
    // ph1: reads A0/A2,B; stages B0,B1(t+1)
    LD_A(0); LD_B(0);
    STG_B(0, t1, dB); STG_B(1, t1, dB);
    BAR; LGKM0; SCHB; PRIO(1); MM(0, 0); PRIO(0); SCHB; BAR;
    // ph2: stages B2,B3(t+1)
    LD_B(1);
    STG_B(2, t1, dB); STG_B(3, t1, dB);
    BAR; LGKM0; SCHB; PRIO(1); MM(0, 1); PRIO(0); SCHB; BAR;
    // ph3: reads A1/A3; stages A0,A2(t+2) into regions freed after ph2
    LD_A(1); LD_B(0);
    STG_A(0, t2, dA); STG_A(2, t2, dA);
    BAR; LGKM0; SCHB; PRIO(1); MM(1, 0); PRIO(0); SCHB; BAR;
    // ph4: stages A1,A3(t+2) into regions freed after ph3
    LD_B(1);
    STG_A(1, t2, dA); STG_A(3, t2, dA);
    BAR; LGKM0; SCHB; PRIO(1); MM(1, 1); PRIO(0); SCHB;
    VM(4);  // oldest 8 = A(t+1)x4 + B(t+1)x4 done; A(t+2)x4 stay in flight
    BAR;
  }

  // tile 14: stage B(15) only; drain all at end (VM(0): A(15)+B(15))
  {
    const int t = NT - 2;
    const char* Ab = lds + (t & 1) * LDS_TILE;
    const char* Bb = Ab + 32768;
    char* dB = lds + ((t + 1) & 1) * LDS_TILE;
    const int t1 = t + 1;
    LD_A(0); LD_B(0);
    STG_B(0, t1, dB); STG_B(1, t1, dB);
    BAR; LGKM0; SCHB; PRIO(1); MM(0, 0); PRIO(0); SCHB; BAR;
    LD_B(1);
    STG_B(2, t1, dB); STG_B(3, t1, dB);
    BAR; LGKM0; SCHB; PRIO(1); MM(0, 1); PRIO(0); SCHB; BAR;
    LD_A(1); LD_B(0);
    BAR; LGKM0; SCHB; PRIO(1); MM(1, 0); PRIO(0); SCHB; BAR;
    LD_B(1);
    BAR; LGKM0; SCHB; PRIO(1); MM(1, 1); PRIO(0); SCHB;
    VM(0);
    BAR;
  }

  // tile 15: bare compute
  {
    const char* Ab = lds + ((NT - 1) & 1) * LDS_TILE;
    const char* Bb = Ab + 32768;
    LD_A(0); LD_B(0);
    BAR; LGKM0; SCHB; PRIO(1); MM(0, 0); PRIO(0); SCHB; BAR;
    LD_B(1);
    BAR; LGKM0; SCHB; PRIO(1); MM(0, 1); PRIO(0); SCHB; BAR;
    LD_A(1); LD_B(0);
    BAR; LGKM0; SCHB; PRIO(1); MM(1, 0); PRIO(0); SCHB; BAR;
    LD_B(1);
    BAR; LGKM0; SCHB; PRIO(1); MM(1, 1); PRIO(0); SCHB;
  }

  // epilogue: C/D layout col=l&15, row=(l>>4)*4+j; scale by dtab (LDS)
  const int lc0 = wc * 64 + l15;
  float dv[4];
#pragma unroll
  for (int nf = 0; nf < 4; ++nf) dv[nf] = dtab[lc0 + nf * 16];
#pragma unroll
  for (int mf = 0; mf < 8; ++mf) {
#pragma unroll
    for (int j = 0; j < 4; ++j) {
      const int row = m0 + wr * 128 + mf * 16 + lhi * 4 + j;
      float* orow = out + (size_t)row * 1024 + n0 + lc0;
#pragma unroll
      for (int nf = 0; nf < 4; ++nf) orow[nf * 16] = acc[mf][nf][j] * dv[nf];
    }
  }
}

// ---------------------------------------------------------------------------
extern "C" void kernel_launch(void* const* d_in, const int* in_sizes, int n_in,
                              void* d_out, int out_size, void* d_ws, size_t ws_size,
                              hipStream_t stream) {
  const float* Efou = (const float*)d_in[0];  // 32*1024*1024 fp32
  const float* y    = (const float*)d_in[1];  // 32*1024 fp32
  const float* W    = (const float*)d_in[2];  // 1024*1024 fp32
  float* out = (float*)d_out;

  unsigned short* X  = (unsigned short*)d_ws;               // 64 MB bf16
  unsigned short* WT = X + (size_t)32768 * 1024;            // 2 MB bf16
  float* dpart       = (float*)(WT + (size_t)1024 * 1024);  // 4 MB fp32

  hipFuncSetAttribute((const void*)gemm8d_kernel,
                      hipFuncAttributeMaxDynamicSharedMemorySize, 132096);

  prep_kernel<<<dim3(4, 32), 256, 0, stream>>>(y, W, dpart, WT);
  xconv_kernel<<<2048, 256, 0, stream>>>((const float4*)Efou, y, X);
  gemm8d_kernel<<<512, 512, 132096, stream>>>(X, WT, dpart, out);
}